// Round 5
// baseline (1388.797 us; speedup 1.0000x reference)
//
#include <hip/hip_runtime.h>
#include <math.h>

#define F 64
#define PR_ROWS 16  // rows per block in fused prop kernels (4 rows/wave)

static __device__ __forceinline__ ushort f2bf(float f) {
    uint u = __float_as_uint(f);
    uint r = (u + 0x7fffu + ((u >> 16) & 1u)) >> 16;  // RNE
    return (ushort)r;
}
static __device__ __forceinline__ float bf2f(ushort v) {
    return __uint_as_float(((uint)v) << 16);
}

// ---------- CSR build ----------

__global__ __launch_bounds__(256) void deg_kernel(const int* __restrict__ ei, int E,
                                                  int* __restrict__ deg) {
    int e = blockIdx.x * 256 + threadIdx.x;
    if (e >= E) return;
    int r = ei[e], c = ei[E + e];
    if (r != c) atomicAdd(&deg[r], 1);
}

__global__ __launch_bounds__(256) void scan1_kernel(const int* __restrict__ deg,
                                                    int* __restrict__ rp,
                                                    int* __restrict__ bsum, int Nv) {
    __shared__ int sh[256];
    int t = threadIdx.x;
    int base = blockIdx.x * 1024 + t * 4;
    int v0 = (base + 0 < Nv) ? deg[base + 0] : 0;
    int v1 = (base + 1 < Nv) ? deg[base + 1] : 0;
    int v2 = (base + 2 < Nv) ? deg[base + 2] : 0;
    int v3 = (base + 3 < Nv) ? deg[base + 3] : 0;
    int s = v0 + v1 + v2 + v3;
    sh[t] = s;
    __syncthreads();
    for (int off = 1; off < 256; off <<= 1) {
        int a = (t >= off) ? sh[t - off] : 0;
        __syncthreads();
        sh[t] += a;
        __syncthreads();
    }
    int run = sh[t] - s;
    run += v0; if (base + 0 < Nv) rp[base + 1] = run;
    run += v1; if (base + 1 < Nv) rp[base + 2] = run;
    run += v2; if (base + 2 < Nv) rp[base + 3] = run;
    run += v3; if (base + 3 < Nv) rp[base + 4] = run;
    if (t == 255) bsum[blockIdx.x] = sh[255];
}

__global__ __launch_bounds__(256) void scan2_kernel(int* __restrict__ bsum, int nb) {
    __shared__ int sh[256];
    int t = threadIdx.x;
    int v = (t < nb) ? bsum[t] : 0;
    sh[t] = v;
    __syncthreads();
    for (int off = 1; off < 256; off <<= 1) {
        int a = (t >= off) ? sh[t - off] : 0;
        __syncthreads();
        sh[t] += a;
        __syncthreads();
    }
    if (t < nb) bsum[t] = sh[t] - v;
}

// scan3 + dinv fused
__global__ __launch_bounds__(256) void scan3_kernel(int* __restrict__ rp,
                                                    const int* __restrict__ bsum,
                                                    const int* __restrict__ deg,
                                                    float* __restrict__ dinv, int Nv) {
    int i = blockIdx.x * 256 + threadIdx.x;
    if (i == 0) rp[0] = 0;
    if (i < Nv) {
        rp[i + 1] += bsum[i >> 10];
        int d = deg[i];
        dinv[i] = d > 0 ? rsqrtf((float)d) : 0.f;
    }
}

__global__ __launch_bounds__(256) void scatter_kernel(const int* __restrict__ ei, int E,
                                                      const int* __restrict__ rp,
                                                      int* __restrict__ fill,
                                                      const float* __restrict__ dinv,
                                                      int2* __restrict__ ce) {
    int e = blockIdx.x * 256 + threadIdx.x;
    if (e >= E) return;
    int r = ei[e], c = ei[E + e];
    if (r == c) return;
    int slot = rp[r] + atomicAdd(&fill[r], 1);
    float w = -dinv[r] * dinv[c];
    ce[slot] = make_int2(c, __float_as_int(w));
}

// ---------- f32 -> bf16 bulk convert ----------

__global__ __launch_bounds__(256) void tobf16_kernel(const float4* __restrict__ src,
                                                     ushort4* __restrict__ dst, int n4) {
    int i = blockIdx.x * 256 + threadIdx.x;
    if (i >= n4) return;
    float4 v = src[i];
    dst[i] = make_ushort4(f2bf(v.x), f2bf(v.y), f2bf(v.z), f2bf(v.w));
}

// ---------- shared device pieces ----------

// 8 independent miss chains over one CSR row; bf16 gather source.
static __device__ __forceinline__ float gather8(const ushort* __restrict__ src,
                                                const int2* __restrict__ ce,
                                                int s, int e, int lane) {
    float s0 = 0.f, s1 = 0.f, s2 = 0.f, s3 = 0.f;
    float s4 = 0.f, s5 = 0.f, s6 = 0.f, s7 = 0.f;
    int p = s;
    for (; p + 8 <= e; p += 8) {
        int2 c0 = ce[p + 0], c1 = ce[p + 1], c2 = ce[p + 2], c3 = ce[p + 3];
        int2 c4 = ce[p + 4], c5 = ce[p + 5], c6 = ce[p + 6], c7 = ce[p + 7];
        s0 = fmaf(__int_as_float(c0.y), bf2f(src[(size_t)c0.x * F + lane]), s0);
        s1 = fmaf(__int_as_float(c1.y), bf2f(src[(size_t)c1.x * F + lane]), s1);
        s2 = fmaf(__int_as_float(c2.y), bf2f(src[(size_t)c2.x * F + lane]), s2);
        s3 = fmaf(__int_as_float(c3.y), bf2f(src[(size_t)c3.x * F + lane]), s3);
        s4 = fmaf(__int_as_float(c4.y), bf2f(src[(size_t)c4.x * F + lane]), s4);
        s5 = fmaf(__int_as_float(c5.y), bf2f(src[(size_t)c5.x * F + lane]), s5);
        s6 = fmaf(__int_as_float(c6.y), bf2f(src[(size_t)c6.x * F + lane]), s6);
        s7 = fmaf(__int_as_float(c7.y), bf2f(src[(size_t)c7.x * F + lane]), s7);
    }
    for (; p < e; p++) {
        int2 c0 = ce[p];
        s0 = fmaf(__int_as_float(c0.y), bf2f(src[(size_t)c0.x * F + lane]), s0);
    }
    return ((s0 + s1) + (s2 + s3)) + ((s4 + s5) + (s6 + s7));
}

// out[lane] = sum_j row_bf16[j] * wr[j]; rowpk is a uniform LDS address
// (broadcast reads, no bank conflicts); 2 bf16 unpacked per dword.
static __device__ __forceinline__ float row_mm(const uint* __restrict__ rowpk,
                                               const float* __restrict__ wr) {
    float a = 0.f;
#pragma unroll
    for (int j2 = 0; j2 < 32; j2++) {
        uint pk = rowpk[j2];
        a = fmaf(__uint_as_float(pk << 16), wr[2 * j2], a);
        a = fmaf(__uint_as_float(pk & 0xFFFF0000u), wr[2 * j2 + 1], a);
    }
    return a;
}

// ---------- level 1 (fused): T1 = L_hat@x ; acc = x@W0 + T1@W1 ----------

__global__ __launch_bounds__(256) void prop_first(const float* __restrict__ x,
                                                  const ushort* __restrict__ xh,
                                                  float* __restrict__ Toutf,
                                                  ushort* __restrict__ Touth,
                                                  const int* __restrict__ rp,
                                                  const int2* __restrict__ ce,
                                                  const float* __restrict__ W0,
                                                  const float* __restrict__ W1,
                                                  float* __restrict__ acc, int Nv) {
    __shared__ __align__(16) ushort ush[PR_ROWS][F];
    int wave = threadIdx.x >> 6, lane = threadIdx.x & 63;
    int rbase = blockIdx.x * PR_ROWS + wave * 4;

#pragma unroll
    for (int r = 0; r < 4; r++) {
        int i = rbase + r;
        bool act = i < Nv;
        int ii = act ? i : 0;
        float sum = gather8(xh, ce, rp[ii], rp[ii + 1], lane);
        if (act) Toutf[(size_t)i * F + lane] = sum;  // T1 f32 (tm2 at level 3)
        ush[wave * 4 + r][lane] = f2bf(sum);
    }
    __syncthreads();
    {   // T1 bf16, cooperative full-line stores (16 rows * 128B = 128 uint4)
        int t = threadIdx.x;
        if (t < 128) {
            int row = t >> 3;
            if (blockIdx.x * PR_ROWS + row < Nv)
                ((uint4*)Touth)[(size_t)blockIdx.x * 128 + t] = ((const uint4*)ush)[t];
        }
    }
    float wr[F];
#pragma unroll
    for (int j = 0; j < F; j++) wr[j] = W0[j * F + lane];  // column `lane` of W0
    float a0[4];
#pragma unroll
    for (int r = 0; r < 4; r++) {
        int i = rbase + r;
        int ii = i < Nv ? i : 0;
        float xv = x[(size_t)ii * F + lane];
        float a = 0.f;
#pragma unroll
        for (int j = 0; j < F; j++) a = fmaf(__shfl(xv, j, 64), wr[j], a);
        a0[r] = a;
    }
#pragma unroll
    for (int j = 0; j < F; j++) wr[j] = W1[j * F + lane];
#pragma unroll
    for (int r = 0; r < 4; r++) {
        int i = rbase + r;
        if (i < Nv)
            acc[(size_t)i * F + lane] = a0[r] + row_mm((const uint*)ush[wave * 4 + r], wr);
    }
}

// ---------- levels 2..K-2 (fused): Tk = 2*L@T_{k-1} - T_{k-2}; acc += Tk@Wk ----------

__global__ __launch_bounds__(256) void prop_mid(const ushort* __restrict__ Tm1h,
                                                const float* __restrict__ Tm2,
                                                float* __restrict__ Toutf,
                                                ushort* __restrict__ Touth,
                                                const int* __restrict__ rp,
                                                const int2* __restrict__ ce,
                                                const float* __restrict__ Wk,
                                                float* __restrict__ acc,
                                                int Nv, int store_f) {
    __shared__ __align__(16) ushort ush[PR_ROWS][F];
    int wave = threadIdx.x >> 6, lane = threadIdx.x & 63;
    int rbase = blockIdx.x * PR_ROWS + wave * 4;

#pragma unroll
    for (int r = 0; r < 4; r++) {
        int i = rbase + r;
        bool act = i < Nv;
        int ii = act ? i : 0;
        float tm2 = Tm2[(size_t)ii * F + lane];  // prefetch before gather
        float sum = gather8(Tm1h, ce, rp[ii], rp[ii + 1], lane);
        float tk = fmaf(2.f, sum, -tm2);
        if (act && store_f) Toutf[(size_t)i * F + lane] = tk;
        ush[wave * 4 + r][lane] = f2bf(tk);
    }
    __syncthreads();
    {
        int t = threadIdx.x;
        if (t < 128) {
            int row = t >> 3;
            if (blockIdx.x * PR_ROWS + row < Nv)
                ((uint4*)Touth)[(size_t)blockIdx.x * 128 + t] = ((const uint4*)ush)[t];
        }
    }
    float wr[F];
#pragma unroll
    for (int j = 0; j < F; j++) wr[j] = Wk[j * F + lane];
#pragma unroll
    for (int r = 0; r < 4; r++) {
        int i = rbase + r;
        if (i < Nv)
            acc[(size_t)i * F + lane] += row_mm((const uint*)ush[wave * 4 + r], wr);
    }
}

// ---------- level K-1 (fused): last Tk; out = ELU(LN(acc + Tk@Wk + bias)) ----------

__global__ __launch_bounds__(256) void prop_last(const ushort* __restrict__ Tm1h,
                                                 const float* __restrict__ Tm2,
                                                 const int* __restrict__ rp,
                                                 const int2* __restrict__ ce,
                                                 const float* __restrict__ Wk,
                                                 const float* __restrict__ bias,
                                                 const float* __restrict__ lnw,
                                                 const float* __restrict__ lnb,
                                                 float* __restrict__ io, int Nv) {
    __shared__ __align__(16) ushort ush[PR_ROWS][F];
    int wave = threadIdx.x >> 6, lane = threadIdx.x & 63;
    int rbase = blockIdx.x * PR_ROWS + wave * 4;

#pragma unroll
    for (int r = 0; r < 4; r++) {
        int i = rbase + r;
        bool act = i < Nv;
        int ii = act ? i : 0;
        float tm2 = Tm2[(size_t)ii * F + lane];
        float sum = gather8(Tm1h, ce, rp[ii], rp[ii + 1], lane);
        float tk = fmaf(2.f, sum, -tm2);
        ush[wave * 4 + r][lane] = f2bf(tk);
    }
    // no cross-wave LDS use: each wave reads only rows it wrote (compiler
    // inserts the lgkmcnt wait); no barrier needed.
    float wr[F];
#pragma unroll
    for (int j = 0; j < F; j++) wr[j] = Wk[j * F + lane];
    float bv = bias[lane], gw = lnw[lane], gb = lnb[lane];
#pragma unroll
    for (int r = 0; r < 4; r++) {
        int i = rbase + r;
        if (i >= Nv) break;
        float v = io[(size_t)i * F + lane]
                + row_mm((const uint*)ush[wave * 4 + r], wr) + bv;
        float s = v;
#pragma unroll
        for (int off = 1; off < 64; off <<= 1) s += __shfl_xor(s, off, 64);
        float mu = s * (1.f / F);
        float d = v - mu;
        float q = d * d;
#pragma unroll
        for (int off = 1; off < 64; off <<= 1) q += __shfl_xor(q, off, 64);
        float y = d * rsqrtf(q * (1.f / F) + 1e-5f) * gw + gb;
        io[(size_t)i * F + lane] = y > 0.f ? y : expm1f(y);
    }
}

// ---------- host ----------

extern "C" void kernel_launch(void* const* d_in, const int* in_sizes, int n_in,
                              void* d_out, int out_size, void* d_ws, size_t ws_size,
                              hipStream_t stream) {
    (void)n_in; (void)out_size;
    const float* x    = (const float*)d_in[0];
    const int*   ei   = (const int*)d_in[1];
    const float* W    = (const float*)d_in[2];
    const float* bias = (const float*)d_in[3];
    const float* lnw  = (const float*)d_in[4];
    const float* lnb  = (const float*)d_in[5];
    float* out = (float*)d_out;

    int Nv = in_sizes[0] / F;
    int E  = in_sizes[1] / 2;
    int K  = in_sizes[2] / (F * F);

    char* base = (char*)d_ws;
    size_t off = 0;
    auto alloc = [&](size_t b) -> void* {
        void* p = base + off;
        off += (b + 255) & ~(size_t)255;
        return p;
    };
    int*    deg  = (int*)alloc((size_t)Nv * 4);
    int*    fill = (int*)alloc((size_t)Nv * 4);
    int*    rp   = (int*)alloc(((size_t)Nv + 1) * 4);
    int     nb   = (Nv + 1023) / 1024;
    int*    bsum = (int*)alloc((size_t)nb * 4);
    float*  dinv = (float*)alloc((size_t)Nv * 4);
    int2*   ce   = (int2*)alloc((size_t)E * 8);
    float*  Ta   = (float*)alloc((size_t)Nv * F * 4);      // T_k f32, k odd
    float*  Tb   = (float*)alloc((size_t)Nv * F * 4);      // T_k f32, k even
    ushort* xh   = (ushort*)alloc((size_t)Nv * F * 2 + 2048);
    ushort* B1   = (ushort*)alloc((size_t)Nv * F * 2 + 2048);  // T_k bf16, k odd
    ushort* B2   = (ushort*)alloc((size_t)Nv * F * 2 + 2048);  // T_k bf16, k even
    if (off > ws_size) return;  // ~105 MB required

    hipMemsetAsync(deg, 0, (size_t)Nv * 4, stream);
    hipMemsetAsync(fill, 0, (size_t)Nv * 4, stream);

    int gE = (E + 255) / 256, gN = (Nv + 255) / 256;
    deg_kernel<<<gE, 256, 0, stream>>>(ei, E, deg);
    scan1_kernel<<<nb, 256, 0, stream>>>(deg, rp, bsum, Nv);
    scan2_kernel<<<1, 256, 0, stream>>>(bsum, nb);
    scan3_kernel<<<gN, 256, 0, stream>>>(rp, bsum, deg, dinv, Nv);
    scatter_kernel<<<gE, 256, 0, stream>>>(ei, E, rp, fill, dinv, ce);

    int n4 = (Nv * F) / 4;
    tobf16_kernel<<<(n4 + 255) / 256, 256, 0, stream>>>((const float4*)x, (ushort4*)xh, n4);

    int gP = (Nv + PR_ROWS - 1) / PR_ROWS;  // 6250 blocks @ N=100000

    // level 1: T1 = L@x ; acc = x@W0 + T1@W1  (acc pure write)
    prop_first<<<gP, 256, 0, stream>>>(x, xh, Ta, B1, rp, ce,
                                       W, W + (size_t)F * F, out, Nv);

    // levels 2..K-2
    const ushort* tm1h = B1;
    for (int k = 2; k <= K - 2; k++) {
        float*  tof = (k & 1) ? Ta : Tb;   // same buffer T_{k-2} lives in: in-place,
        ushort* toh = (k & 1) ? B1 : B2;   // each thread reads its row before writing
        const float* tm2 = (k == 2) ? x : (const float*)tof;
        int store_f = (k <= K - 3) ? 1 : 0;
        prop_mid<<<gP, 256, 0, stream>>>(tm1h, tm2, tof, toh, rp, ce,
                                         W + (size_t)k * F * F, out, Nv, store_f);
        tm1h = toh;
    }

    // level K-1 + bias + LayerNorm + ELU
    {
        int k = K - 1;
        const float* tm2 = (k & 1) ? Ta : Tb;
        prop_last<<<gP, 256, 0, stream>>>(tm1h, tm2, rp, ce,
                                          W + (size_t)k * F * F, bias, lnw, lnb,
                                          out, Nv);
    }
}

// Round 6
// 767.284 us; speedup vs baseline: 1.8100x; 1.8100x over previous
//
#include <hip/hip_runtime.h>
#include <math.h>

#define F 64
#define PR_ROWS 16  // rows per block in prop kernel (4 rows/wave)

using short8 = __attribute__((ext_vector_type(8))) short;
using f32x4  = __attribute__((ext_vector_type(4))) float;

static __device__ __forceinline__ ushort f2bf(float f) {
    uint u = __float_as_uint(f);
    uint r = (u + 0x7fffu + ((u >> 16) & 1u)) >> 16;  // RNE
    return (ushort)r;
}
static __device__ __forceinline__ float bf2f(ushort v) {
    return __uint_as_float(((uint)v) << 16);
}

// ---------- CSR build ----------

__global__ __launch_bounds__(256) void deg_kernel(const int* __restrict__ ei, int E,
                                                  int* __restrict__ deg) {
    int e = blockIdx.x * 256 + threadIdx.x;
    if (e >= E) return;
    int r = ei[e], c = ei[E + e];
    if (r != c) atomicAdd(&deg[r], 1);
}

__global__ __launch_bounds__(256) void scan1_kernel(const int* __restrict__ deg,
                                                    int* __restrict__ rp,
                                                    int* __restrict__ bsum, int Nv) {
    __shared__ int sh[256];
    int t = threadIdx.x;
    int base = blockIdx.x * 1024 + t * 4;
    int v0 = (base + 0 < Nv) ? deg[base + 0] : 0;
    int v1 = (base + 1 < Nv) ? deg[base + 1] : 0;
    int v2 = (base + 2 < Nv) ? deg[base + 2] : 0;
    int v3 = (base + 3 < Nv) ? deg[base + 3] : 0;
    int s = v0 + v1 + v2 + v3;
    sh[t] = s;
    __syncthreads();
    for (int off = 1; off < 256; off <<= 1) {
        int a = (t >= off) ? sh[t - off] : 0;
        __syncthreads();
        sh[t] += a;
        __syncthreads();
    }
    int run = sh[t] - s;
    run += v0; if (base + 0 < Nv) rp[base + 1] = run;
    run += v1; if (base + 1 < Nv) rp[base + 2] = run;
    run += v2; if (base + 2 < Nv) rp[base + 3] = run;
    run += v3; if (base + 3 < Nv) rp[base + 4] = run;
    if (t == 255) bsum[blockIdx.x] = sh[255];
}

__global__ __launch_bounds__(256) void scan2_kernel(int* __restrict__ bsum, int nb) {
    __shared__ int sh[256];
    int t = threadIdx.x;
    int v = (t < nb) ? bsum[t] : 0;
    sh[t] = v;
    __syncthreads();
    for (int off = 1; off < 256; off <<= 1) {
        int a = (t >= off) ? sh[t - off] : 0;
        __syncthreads();
        sh[t] += a;
        __syncthreads();
    }
    if (t < nb) bsum[t] = sh[t] - v;
}

// scan3 + dinv fused
__global__ __launch_bounds__(256) void scan3_kernel(int* __restrict__ rp,
                                                    const int* __restrict__ bsum,
                                                    const int* __restrict__ deg,
                                                    float* __restrict__ dinv, int Nv) {
    int i = blockIdx.x * 256 + threadIdx.x;
    if (i == 0) rp[0] = 0;
    if (i < Nv) {
        rp[i + 1] += bsum[i >> 10];
        int d = deg[i];
        dinv[i] = d > 0 ? rsqrtf((float)d) : 0.f;
    }
}

__global__ __launch_bounds__(256) void scatter_kernel(const int* __restrict__ ei, int E,
                                                      const int* __restrict__ rp,
                                                      int* __restrict__ fill,
                                                      const float* __restrict__ dinv,
                                                      int2* __restrict__ ce) {
    int e = blockIdx.x * 256 + threadIdx.x;
    if (e >= E) return;
    int r = ei[e], c = ei[E + e];
    if (r == c) return;
    int slot = rp[r] + atomicAdd(&fill[r], 1);
    float w = -dinv[r] * dinv[c];
    ce[slot] = make_int2(c, __float_as_int(w));
}

// ---------- f32 -> bf16 bulk convert (x -> slice0) ----------

__global__ __launch_bounds__(256) void tobf16_kernel(const float4* __restrict__ src,
                                                     ushort4* __restrict__ dst, int n4) {
    int i = blockIdx.x * 256 + threadIdx.x;
    if (i >= n4) return;
    float4 v = src[i];
    dst[i] = make_ushort4(f2bf(v.x), f2bf(v.y), f2bf(v.z), f2bf(v.w));
}

// ---------- W [K*64][64] f32 -> WbT [64][K*64] bf16 (transposed) ----------

__global__ __launch_bounds__(256) void wconv_kernel(const float* __restrict__ W,
                                                    ushort* __restrict__ WbT, int KK) {
    int t = blockIdx.x * 256 + threadIdx.x;
    if (t >= KK * F) return;
    int col = t / KK, kk = t - col * KK;
    WbT[t] = f2bf(W[(size_t)kk * F + col]);
}

// ---------- lean prop: tk = 2*L_hat@T_{k-1} - T_{k-2} (or L@x for first) ----------
// 64 VGPR, high occupancy. bf16 gather source; f32 recurrence; bf16 output
// LDS-staged and stored as full-line uint4 (avoids sub-sector RMW).

__global__ __launch_bounds__(256) void prop_v4(const ushort* __restrict__ Tm1h,
                                               const float* __restrict__ Tm2,
                                               float* __restrict__ Toutf,
                                               ushort* __restrict__ Touth,
                                               const int* __restrict__ rp,
                                               const int2* __restrict__ ce,
                                               int Nv, int first, int store_f) {
    __shared__ __align__(16) ushort ush[PR_ROWS][F];
    int wave = threadIdx.x >> 6, lane = threadIdx.x & 63;
    int rbase = blockIdx.x * PR_ROWS + wave * 4;

    for (int r = 0; r < 4; r++) {
        int i = rbase + r;
        bool act = i < Nv;
        int ii = act ? i : 0;
        float tm2 = first ? 0.f : Tm2[(size_t)ii * F + lane];  // prefetch early
        int s = rp[ii], e = rp[ii + 1];
        float s0 = 0.f, s1 = 0.f, s2 = 0.f, s3 = 0.f;
        float s4 = 0.f, s5 = 0.f, s6 = 0.f, s7 = 0.f;
        int p = s;
        for (; p + 8 <= e; p += 8) {  // 8 independent miss chains
            int2 c0 = ce[p + 0], c1 = ce[p + 1], c2 = ce[p + 2], c3 = ce[p + 3];
            int2 c4 = ce[p + 4], c5 = ce[p + 5], c6 = ce[p + 6], c7 = ce[p + 7];
            s0 = fmaf(__int_as_float(c0.y), bf2f(Tm1h[(size_t)c0.x * F + lane]), s0);
            s1 = fmaf(__int_as_float(c1.y), bf2f(Tm1h[(size_t)c1.x * F + lane]), s1);
            s2 = fmaf(__int_as_float(c2.y), bf2f(Tm1h[(size_t)c2.x * F + lane]), s2);
            s3 = fmaf(__int_as_float(c3.y), bf2f(Tm1h[(size_t)c3.x * F + lane]), s3);
            s4 = fmaf(__int_as_float(c4.y), bf2f(Tm1h[(size_t)c4.x * F + lane]), s4);
            s5 = fmaf(__int_as_float(c5.y), bf2f(Tm1h[(size_t)c5.x * F + lane]), s5);
            s6 = fmaf(__int_as_float(c6.y), bf2f(Tm1h[(size_t)c6.x * F + lane]), s6);
            s7 = fmaf(__int_as_float(c7.y), bf2f(Tm1h[(size_t)c7.x * F + lane]), s7);
        }
        for (; p < e; p++) {
            int2 c0 = ce[p];
            s0 = fmaf(__int_as_float(c0.y), bf2f(Tm1h[(size_t)c0.x * F + lane]), s0);
        }
        float sum = ((s0 + s1) + (s2 + s3)) + ((s4 + s5) + (s6 + s7));
        float tk = first ? sum : fmaf(2.f, sum, -tm2);
        if (act && store_f) Toutf[(size_t)i * F + lane] = tk;
        ush[wave * 4 + r][lane] = f2bf(tk);
    }
    __syncthreads();
    int t = threadIdx.x;
    if (t < 128) {  // 16 rows * 128B = 128 uint4, contiguous full lines
        int row = t >> 3;
        if (blockIdx.x * PR_ROWS + row < Nv)
            ((uint4*)Touth)[(size_t)blockIdx.x * 128 + t] = ((const uint4*)ush)[t];
    }
}

// ---------- MFMA pair-GEMM: out (=|+=) [A0|A1] @ WbT_pair ----------
// Wave strip = 16 rows x 64 cols, K=128 (two bf16 slices).
// A-frag: row = lane&15, k = (lane>>4)*8 + [0..8) (contiguous 16B load).
// B-frag: col = lane&15, same k pattern from WbT[col][kk] (contiguous 16B).
// C/D: col = lane&15, row = (lane>>4)*4 + reg  [verified m89 mapping].
// Last pair fuses +bias, LayerNorm (16-lane-group shfl_xor reduce), ELU.

__global__ __launch_bounds__(256) void gemm_pair(const ushort* __restrict__ A0,
                                                 const ushort* __restrict__ A1,
                                                 const ushort* __restrict__ WbT,
                                                 int kkbase, int KK,
                                                 float* __restrict__ out,
                                                 const float* __restrict__ bias,
                                                 const float* __restrict__ lnw,
                                                 const float* __restrict__ lnb,
                                                 int Nv, int first, int last) {
    int wave = threadIdx.x >> 6, lane = threadIdx.x & 63;
    int rbase = (blockIdx.x * 4 + wave) * 16;
    if (rbase >= Nv) return;
    int r15 = lane & 15, kg = lane >> 4;
    int arow = rbase + r15;
    if (arow >= Nv) arow = Nv - 1;  // clamp; clamped rows never stored

    f32x4 acc[4];
#pragma unroll
    for (int t = 0; t < 4; t++) acc[t] = (f32x4){0.f, 0.f, 0.f, 0.f};

    const ushort* As[2] = {A0, A1};
#pragma unroll
    for (int s = 0; s < 4; s++) {  // 4 K-steps of 32
        int kb = s * 32;
        short8 a = *(const short8*)(As[s >> 1] + (size_t)arow * F + (kb & 63) + kg * 8);
#pragma unroll
        for (int t = 0; t < 4; t++) {
            int col = t * 16 + r15;
            short8 b = *(const short8*)(WbT + (size_t)col * KK + kkbase + kb + kg * 8);
            acc[t] = __builtin_amdgcn_mfma_f32_16x16x32_bf16(a, b, acc[t], 0, 0, 0);
        }
    }

    if (!last) {
#pragma unroll
        for (int t = 0; t < 4; t++) {
            int col = t * 16 + r15;
#pragma unroll
            for (int j = 0; j < 4; j++) {
                int row = rbase + kg * 4 + j;
                if (row < Nv) {
                    size_t idx = (size_t)row * F + col;
                    out[idx] = first ? acc[t][j] : out[idx] + acc[t][j];
                }
            }
        }
    } else {
        float bc[4], wc[4], gc[4];
#pragma unroll
        for (int t = 0; t < 4; t++) {
            int col = t * 16 + r15;
            bc[t] = bias[col]; wc[t] = lnw[col]; gc[t] = lnb[col];
        }
#pragma unroll
        for (int j = 0; j < 4; j++) {
            int row = rbase + kg * 4 + j;
            int rr = row < Nv ? row : Nv - 1;  // whole 16-lane group uniform
            float v[4];
            float s = 0.f;
#pragma unroll
            for (int t = 0; t < 4; t++) {
                int col = t * 16 + r15;
                v[t] = out[(size_t)rr * F + col] + acc[t][j] + bc[t];
                s += v[t];
            }
            s += __shfl_xor(s, 1, 64); s += __shfl_xor(s, 2, 64);
            s += __shfl_xor(s, 4, 64); s += __shfl_xor(s, 8, 64);
            float mu = s * (1.f / F);
            float q = 0.f;
#pragma unroll
            for (int t = 0; t < 4; t++) { float d = v[t] - mu; q += d * d; }
            q += __shfl_xor(q, 1, 64); q += __shfl_xor(q, 2, 64);
            q += __shfl_xor(q, 4, 64); q += __shfl_xor(q, 8, 64);
            float inv = rsqrtf(q * (1.f / F) + 1e-5f);
            if (row < Nv) {
#pragma unroll
                for (int t = 0; t < 4; t++) {
                    int col = t * 16 + r15;
                    float y = (v[t] - mu) * inv * wc[t] + gc[t];
                    out[(size_t)row * F + col] = y > 0.f ? y : expm1f(y);
                }
            }
        }
    }
}

// ---------- host ----------

extern "C" void kernel_launch(void* const* d_in, const int* in_sizes, int n_in,
                              void* d_out, int out_size, void* d_ws, size_t ws_size,
                              hipStream_t stream) {
    (void)n_in; (void)out_size;
    const float* x    = (const float*)d_in[0];
    const int*   ei   = (const int*)d_in[1];
    const float* W    = (const float*)d_in[2];
    const float* bias = (const float*)d_in[3];
    const float* lnw  = (const float*)d_in[4];
    const float* lnb  = (const float*)d_in[5];
    float* out = (float*)d_out;

    int Nv = in_sizes[0] / F;
    int E  = in_sizes[1] / 2;
    int K  = in_sizes[2] / (F * F);  // 8 (even, >=4 assumed)
    int KK = K * F;

    char* base = (char*)d_ws;
    size_t off = 0;
    auto alloc = [&](size_t b) -> void* {
        void* p = base + off;
        off += (b + 255) & ~(size_t)255;
        return p;
    };
    int*    deg  = (int*)alloc((size_t)Nv * 4);
    int*    fill = (int*)alloc((size_t)Nv * 4);
    int*    rp   = (int*)alloc(((size_t)Nv + 1) * 4);
    int     nb   = (Nv + 1023) / 1024;
    int*    bsum = (int*)alloc((size_t)nb * 4);
    float*  dinv = (float*)alloc((size_t)Nv * 4);
    int2*   ce   = (int2*)alloc((size_t)E * 8);
    float*  Ta   = (float*)alloc((size_t)Nv * F * 4);          // T_k f32, k odd
    float*  Tb   = (float*)alloc((size_t)Nv * F * 4);          // T_k f32, k even
    ushort* xh   = (ushort*)alloc((size_t)Nv * F * 2 + 2048);  // slice k%3==0
    ushort* B1   = (ushort*)alloc((size_t)Nv * F * 2 + 2048);  // slice k%3==1
    ushort* B2   = (ushort*)alloc((size_t)Nv * F * 2 + 2048);  // slice k%3==2
    ushort* WbT  = (ushort*)alloc((size_t)KK * F * 2);
    if (off > ws_size) return;  // ~105 MB required

    hipMemsetAsync(deg, 0, (size_t)Nv * 4, stream);
    hipMemsetAsync(fill, 0, (size_t)Nv * 4, stream);

    int gE = (E + 255) / 256, gN = (Nv + 255) / 256;
    deg_kernel<<<gE, 256, 0, stream>>>(ei, E, deg);
    scan1_kernel<<<nb, 256, 0, stream>>>(deg, rp, bsum, Nv);
    scan2_kernel<<<1, 256, 0, stream>>>(bsum, nb);
    scan3_kernel<<<gN, 256, 0, stream>>>(rp, bsum, deg, dinv, Nv);
    scatter_kernel<<<gE, 256, 0, stream>>>(ei, E, rp, fill, dinv, ce);

    int n4 = (Nv * F) / 4;
    tobf16_kernel<<<(n4 + 255) / 256, 256, 0, stream>>>((const float4*)x, (ushort4*)xh, n4);
    wconv_kernel<<<(KK * F + 255) / 256, 256, 0, stream>>>(W, WbT, KK);

    int gP = (Nv + PR_ROWS - 1) / PR_ROWS;   // prop grid
    int gG = (Nv + 63) / 64;                 // gemm grid (4 strips/block)

    ushort* bb[3] = {xh, B1, B2};  // slice k lives in bb[k%3]
    for (int k = 1; k < K; k++) {
        float* tof = (k & 1) ? Ta : Tb;
        const float* tm2 = (k < 2) ? nullptr : (k == 2 ? x : (const float*)tof);
        int store_f = (k <= K - 3) ? 1 : 0;
        prop_v4<<<gP, 256, 0, stream>>>(bb[(k - 1) % 3], tm2, tof, bb[k % 3],
                                        rp, ce, Nv, k == 1 ? 1 : 0, store_f);
        if (k & 1) {  // pair p = (k-1, k) complete -> GEMM
            int p = k >> 1;
            gemm_pair<<<gG, 256, 0, stream>>>(bb[(2 * p) % 3], bb[(2 * p + 1) % 3],
                                              WbT, p * 2 * F, KK, out,
                                              bias, lnw, lnb, Nv,
                                              p == 0 ? 1 : 0, k == K - 1 ? 1 : 0);
        }
    }
}

// Round 7
// 551.311 us; speedup vs baseline: 2.5191x; 1.3917x over previous
//
#include <hip/hip_runtime.h>
#include <math.h>

#define F 64
#define PR_ROWS 16  // rows per block in prop kernel (4 rows/wave)

using short8 = __attribute__((ext_vector_type(8))) short;
using f32x4  = __attribute__((ext_vector_type(4))) float;

static __device__ __forceinline__ ushort f2bf(float f) {
    uint u = __float_as_uint(f);
    uint r = (u + 0x7fffu + ((u >> 16) & 1u)) >> 16;  // RNE
    return (ushort)r;
}
static __device__ __forceinline__ float bf2f(ushort v) {
    return __uint_as_float(((uint)v) << 16);
}

// ---------- CSR build (padded rows, column-only edges) ----------

__global__ __launch_bounds__(256) void deg_kernel(const int* __restrict__ ei, int E,
                                                  int* __restrict__ deg) {
    int e = blockIdx.x * 256 + threadIdx.x;
    if (e >= E) return;
    int r = ei[e], c = ei[E + e];
    if (r != c) atomicAdd(&deg[r], 1);
}

// scans PADDED degrees: pdeg = ceil(deg/8)*8
__global__ __launch_bounds__(256) void scan1_kernel(const int* __restrict__ deg,
                                                    int* __restrict__ rp,
                                                    int* __restrict__ bsum, int Nv) {
    __shared__ int sh[256];
    int t = threadIdx.x;
    int base = blockIdx.x * 1024 + t * 4;
    int v0 = (base + 0 < Nv) ? ((deg[base + 0] + 7) & ~7) : 0;
    int v1 = (base + 1 < Nv) ? ((deg[base + 1] + 7) & ~7) : 0;
    int v2 = (base + 2 < Nv) ? ((deg[base + 2] + 7) & ~7) : 0;
    int v3 = (base + 3 < Nv) ? ((deg[base + 3] + 7) & ~7) : 0;
    int s = v0 + v1 + v2 + v3;
    sh[t] = s;
    __syncthreads();
    for (int off = 1; off < 256; off <<= 1) {
        int a = (t >= off) ? sh[t - off] : 0;
        __syncthreads();
        sh[t] += a;
        __syncthreads();
    }
    int run = sh[t] - s;
    run += v0; if (base + 0 < Nv) rp[base + 1] = run;
    run += v1; if (base + 1 < Nv) rp[base + 2] = run;
    run += v2; if (base + 2 < Nv) rp[base + 3] = run;
    run += v3; if (base + 3 < Nv) rp[base + 4] = run;
    if (t == 255) bsum[blockIdx.x] = sh[255];
}

__global__ __launch_bounds__(256) void scan2_kernel(int* __restrict__ bsum, int nb) {
    __shared__ int sh[256];
    int t = threadIdx.x;
    int v = (t < nb) ? bsum[t] : 0;
    sh[t] = v;
    __syncthreads();
    for (int off = 1; off < 256; off <<= 1) {
        int a = (t >= off) ? sh[t - off] : 0;
        __syncthreads();
        sh[t] += a;
        __syncthreads();
    }
    if (t < nb) bsum[t] = sh[t] - v;
}

// scan3 + dinv fused
__global__ __launch_bounds__(256) void scan3_kernel(int* __restrict__ rp,
                                                    const int* __restrict__ bsum,
                                                    const int* __restrict__ deg,
                                                    float* __restrict__ dinv, int Nv) {
    int i = blockIdx.x * 256 + threadIdx.x;
    if (i == 0) rp[0] = 0;
    if (i < Nv) {
        rp[i + 1] += bsum[i >> 10];
        int d = deg[i];
        dinv[i] = d > 0 ? rsqrtf((float)d) : 0.f;
    }
}

// column-only scatter; dinv[c]==0 edges -> sentinel row Nv (w would be 0);
// the LAST arriving edge of each row pads the tail slots with the sentinel.
__global__ __launch_bounds__(256) void scatter_kernel(const int* __restrict__ ei, int E,
                                                      const int* __restrict__ rp,
                                                      int* __restrict__ fill,
                                                      const float* __restrict__ dinv,
                                                      const int* __restrict__ deg,
                                                      int* __restrict__ ce, int Nv) {
    int e = blockIdx.x * 256 + threadIdx.x;
    if (e >= E) return;
    int r = ei[e], c = ei[E + e];
    if (r == c) return;
    int old = atomicAdd(&fill[r], 1);
    ce[rp[r] + old] = (dinv[c] > 0.f) ? c : Nv;
    if (old == deg[r] - 1) {
        int q = rp[r] + deg[r], qe = rp[r + 1];
        for (; q < qe; q++) ce[q] = Nv;
    }
}

// ---------- G0 = bf16(sinv .* x), plus zeroed sentinel row ----------

__global__ __launch_bounds__(256) void tobf16_kernel(const float4* __restrict__ src,
                                                     ushort4* __restrict__ dst,
                                                     const float* __restrict__ dinv,
                                                     int n4, int Nv) {
    int i = blockIdx.x * 256 + threadIdx.x;
    if (i < 16) dst[(size_t)Nv * 16 + i] = make_ushort4(0, 0, 0, 0);  // row Nv = 0
    if (i >= n4) return;
    int row = i >> 4;
    float dr = dinv[row];
    float sv = dr > 0.f ? dr : 1.f;
    float4 v = src[i];
    dst[i] = make_ushort4(f2bf(sv * v.x), f2bf(sv * v.y), f2bf(sv * v.z), f2bf(sv * v.w));
}

// ---------- W [K*64][64] f32 -> WbT [64][K*64] bf16 (transposed) ----------

__global__ __launch_bounds__(256) void wconv_kernel(const float* __restrict__ W,
                                                    ushort* __restrict__ WbT, int KK) {
    int t = blockIdx.x * 256 + threadIdx.x;
    if (t >= KK * F) return;
    int col = t / KK, kk = t - col * KK;
    WbT[t] = f2bf(W[(size_t)kk * F + col]);
}

// ---------- weightless prop: raw = -dinv_r * sum(G[c]); tk = 2*raw - tm2 ----------
// Padded rows: uniform 8-chain iterations, aligned int4 column loads.
// Writes f32 tk (recurrence) and bf16 G = sinv_r * tk (LDS-staged, full-line stores).

__global__ __launch_bounds__(256) void prop_v5(const ushort* __restrict__ Gsrc,
                                               const float* __restrict__ Tm2,
                                               float* __restrict__ Toutf,
                                               ushort* __restrict__ Gout,
                                               const int* __restrict__ rp,
                                               const int* __restrict__ ce,
                                               const float* __restrict__ dinv,
                                               int Nv, int first, int store_f) {
    __shared__ __align__(16) ushort ush[PR_ROWS][F];
    int wave = threadIdx.x >> 6, lane = threadIdx.x & 63;
    int rbase = blockIdx.x * PR_ROWS + wave * 4;

    if (blockIdx.x == 0 && threadIdx.x < 8)  // zero sentinel row of Gout
        ((uint4*)(Gout + (size_t)Nv * F))[threadIdx.x] = make_uint4(0, 0, 0, 0);

    for (int r = 0; r < 4; r++) {
        int i = rbase + r;
        bool act = i < Nv;
        int ii = act ? i : 0;
        float dr = dinv[ii];
        float tm2 = first ? 0.f : Tm2[(size_t)ii * F + lane];  // prefetch early
        int s = rp[ii], e = rp[ii + 1];
        float s0 = 0.f, s1 = 0.f, s2 = 0.f, s3 = 0.f;
        float s4 = 0.f, s5 = 0.f, s6 = 0.f, s7 = 0.f;
        for (int p = s; p < e; p += 8) {  // 8 independent miss chains, no remainder
            int4 q0 = *(const int4*)(ce + p);
            int4 q1 = *(const int4*)(ce + p + 4);
            s0 += bf2f(Gsrc[(size_t)q0.x * F + lane]);
            s1 += bf2f(Gsrc[(size_t)q0.y * F + lane]);
            s2 += bf2f(Gsrc[(size_t)q0.z * F + lane]);
            s3 += bf2f(Gsrc[(size_t)q0.w * F + lane]);
            s4 += bf2f(Gsrc[(size_t)q1.x * F + lane]);
            s5 += bf2f(Gsrc[(size_t)q1.y * F + lane]);
            s6 += bf2f(Gsrc[(size_t)q1.z * F + lane]);
            s7 += bf2f(Gsrc[(size_t)q1.w * F + lane]);
        }
        float sum = ((s0 + s1) + (s2 + s3)) + ((s4 + s5) + (s6 + s7));
        float raw = -dr * sum;
        float tk = first ? raw : fmaf(2.f, raw, -tm2);
        if (act && store_f) Toutf[(size_t)i * F + lane] = tk;
        float sv = dr > 0.f ? dr : 1.f;
        ush[wave * 4 + r][lane] = f2bf(sv * tk);
    }
    __syncthreads();
    int t = threadIdx.x;
    if (t < 128) {  // 16 rows * 128B = 128 uint4 contiguous full lines
        int row = t >> 3;
        if (blockIdx.x * PR_ROWS + row < Nv)
            ((uint4*)Gout)[(size_t)blockIdx.x * 128 + t] = ((const uint4*)ush)[t];
    }
}

// ---------- MFMA GEMM over NSL slices (K = NSL*64) ----------
// Wave strip = 16 rows x 64 cols. A row r holds sinv_r*T; epilogue multiplies
// by s_r = sqrt(deg) (or 1), so out = sum_k T_k @ W_k. LAST fuses bias+LN+ELU.

template <int NSL, int FIRST, int LAST>
__global__ __launch_bounds__(256) void gemm_all(
    const ushort* __restrict__ g0, const ushort* __restrict__ g1,
    const ushort* __restrict__ g2, const ushort* __restrict__ g3,
    const ushort* __restrict__ g4, const ushort* __restrict__ g5,
    const ushort* __restrict__ g6, const ushort* __restrict__ g7,
    const ushort* __restrict__ WbT, int kkbase, int KK,
    float* __restrict__ out, const float* __restrict__ bias,
    const float* __restrict__ lnw, const float* __restrict__ lnb,
    const int* __restrict__ deg, int Nv) {
    const ushort* gs[8] = {g0, g1, g2, g3, g4, g5, g6, g7};
    int wave = threadIdx.x >> 6, lane = threadIdx.x & 63;
    int rbase = (blockIdx.x * 4 + wave) * 16;
    if (rbase >= Nv) return;
    int r15 = lane & 15, kg = lane >> 4;
    int arow = rbase + r15;
    if (arow >= Nv) arow = Nv - 1;  // clamp; clamped rows never stored

    f32x4 acc[4];
#pragma unroll
    for (int t = 0; t < 4; t++) acc[t] = (f32x4){0.f, 0.f, 0.f, 0.f};

#pragma unroll
    for (int st = 0; st < 2 * NSL; st++) {  // K-steps of 32
        const ushort* A = gs[st >> 1];
        short8 a = *(const short8*)(A + (size_t)arow * F + (st & 1) * 32 + kg * 8);
#pragma unroll
        for (int t = 0; t < 4; t++) {
            int col = t * 16 + r15;
            short8 b = *(const short8*)(WbT + (size_t)col * KK + kkbase + st * 32 + kg * 8);
            acc[t] = __builtin_amdgcn_mfma_f32_16x16x32_bf16(a, b, acc[t], 0, 0, 0);
        }
    }

    if (!LAST) {
#pragma unroll
        for (int t = 0; t < 4; t++) {
            int col = t * 16 + r15;
#pragma unroll
            for (int j = 0; j < 4; j++) {
                int row = rbase + kg * 4 + j;
                if (row < Nv) {
                    size_t idx = (size_t)row * F + col;
                    out[idx] = FIRST ? acc[t][j] : out[idx] + acc[t][j];
                }
            }
        }
    } else {
        float bc[4], wc[4], gc[4];
#pragma unroll
        for (int t = 0; t < 4; t++) {
            int col = t * 16 + r15;
            bc[t] = bias[col]; wc[t] = lnw[col]; gc[t] = lnb[col];
        }
#pragma unroll
        for (int j = 0; j < 4; j++) {
            int row = rbase + kg * 4 + j;
            int rr = row < Nv ? row : Nv - 1;  // whole 16-lane group uniform
            int dg = deg[rr];
            float sr = dg > 0 ? sqrtf((float)dg) : 1.f;  // undo sinv row scale
            float v[4];
            float s = 0.f;
#pragma unroll
            for (int t = 0; t < 4; t++) {
                int col = t * 16 + r15;
                float a_ = acc[t][j];
                if (!FIRST) a_ += out[(size_t)rr * F + col];
                v[t] = a_ * sr + bc[t];
                s += v[t];
            }
            s += __shfl_xor(s, 1, 64); s += __shfl_xor(s, 2, 64);
            s += __shfl_xor(s, 4, 64); s += __shfl_xor(s, 8, 64);
            float mu = s * (1.f / F);
            float q = 0.f;
#pragma unroll
            for (int t = 0; t < 4; t++) { float d = v[t] - mu; q += d * d; }
            q += __shfl_xor(q, 1, 64); q += __shfl_xor(q, 2, 64);
            q += __shfl_xor(q, 4, 64); q += __shfl_xor(q, 8, 64);
            float inv = rsqrtf(q * (1.f / F) + 1e-5f);
            if (row < Nv) {
#pragma unroll
                for (int t = 0; t < 4; t++) {
                    int col = t * 16 + r15;
                    float y = (v[t] - mu) * inv * wc[t] + gc[t];
                    out[(size_t)row * F + col] = y > 0.f ? y : expm1f(y);
                }
            }
        }
    }
}

// ---------- host ----------

extern "C" void kernel_launch(void* const* d_in, const int* in_sizes, int n_in,
                              void* d_out, int out_size, void* d_ws, size_t ws_size,
                              hipStream_t stream) {
    (void)n_in; (void)out_size;
    const float* x    = (const float*)d_in[0];
    const int*   ei   = (const int*)d_in[1];
    const float* W    = (const float*)d_in[2];
    const float* bias = (const float*)d_in[3];
    const float* lnw  = (const float*)d_in[4];
    const float* lnb  = (const float*)d_in[5];
    float* out = (float*)d_out;

    int Nv = in_sizes[0] / F;
    int E  = in_sizes[1] / 2;
    int K  = in_sizes[2] / (F * F);  // 8
    int KK = K * F;

    char* base = (char*)d_ws;
    size_t off = 0;
    auto alloc = [&](size_t b) -> void* {
        void* p = base + off;
        off += (b + 255) & ~(size_t)255;
        return p;
    };
    int*    degfill = (int*)alloc((size_t)2 * Nv * 4);  // deg | fill, one memset
    int*    deg  = degfill;
    int*    fill = degfill + Nv;
    int*    rp   = (int*)alloc(((size_t)Nv + 1) * 4);
    int     nb   = (Nv + 1023) / 1024;
    int*    bsum = (int*)alloc((size_t)nb * 4);
    float*  dinv = (float*)alloc((size_t)Nv * 4);
    int*    ce   = (int*)alloc(((size_t)E + 8 * Nv) * 4);  // padded CSR columns
    float*  Ta   = (float*)alloc((size_t)Nv * F * 4);      // T_k f32, k odd
    float*  Tb   = (float*)alloc((size_t)Nv * F * 4);      // T_k f32, k even
    ushort* WbT  = (ushort*)alloc((size_t)KK * F * 2);
    size_t fixed = off;

    size_t gbytes = ((size_t)Nv + 1) * F * 2;  // one bf16 slice incl. sentinel row
    size_t galign = (gbytes + 255) & ~(size_t)255;
    int full = (K == 8 && fixed + 8 * galign <= ws_size) ? 1 : 0;
    int nG = full ? 8 : 3;
    ushort* G[8];
    for (int i = 0; i < nG; i++) G[i] = (ushort*)alloc(gbytes);
    if (off > ws_size) return;

    hipMemsetAsync(degfill, 0, (size_t)2 * Nv * 4, stream);

    int gE = (E + 255) / 256, gN = (Nv + 255) / 256;
    deg_kernel<<<gE, 256, 0, stream>>>(ei, E, deg);
    scan1_kernel<<<nb, 256, 0, stream>>>(deg, rp, bsum, Nv);
    scan2_kernel<<<1, 256, 0, stream>>>(bsum, nb);
    scan3_kernel<<<gN, 256, 0, stream>>>(rp, bsum, deg, dinv, Nv);
    scatter_kernel<<<gE, 256, 0, stream>>>(ei, E, rp, fill, dinv, deg, ce, Nv);

    int n4 = (Nv * F) / 4;
    tobf16_kernel<<<(n4 + 255) / 256, 256, 0, stream>>>((const float4*)x, (ushort4*)G[0],
                                                        dinv, n4, Nv);
    wconv_kernel<<<(KK * F + 255) / 256, 256, 0, stream>>>(W, WbT, KK);

    int gP = (Nv + PR_ROWS - 1) / PR_ROWS;
    int gG = (Nv + 63) / 64;

    for (int k = 1; k < K; k++) {
        float* tof = (k & 1) ? Ta : Tb;
        const float* tm2 = (k < 2) ? nullptr : (k == 2 ? x : (const float*)tof);
        int store_f = (k <= K - 3) ? 1 : 0;
        const ushort* gsrc = full ? G[k - 1] : G[(k - 1) % 3];
        ushort*       gdst = full ? G[k]     : G[k % 3];
        prop_v5<<<gP, 256, 0, stream>>>(gsrc, tm2, tof, gdst, rp, ce, dinv,
                                        Nv, k == 1 ? 1 : 0, store_f);
        if (!full && (k & 1)) {  // pair rotation fallback
            int p = k >> 1;
            const ushort* a0 = G[(2 * p) % 3];
            const ushort* a1 = G[(2 * p + 1) % 3];
            if (p == 0)
                gemm_all<2, 1, 0><<<gG, 256, 0, stream>>>(a0, a1, 0, 0, 0, 0, 0, 0,
                    WbT, p * 128, KK, out, bias, lnw, lnb, deg, Nv);
            else if (k < K - 1)
                gemm_all<2, 0, 0><<<gG, 256, 0, stream>>>(a0, a1, 0, 0, 0, 0, 0, 0,
                    WbT, p * 128, KK, out, bias, lnw, lnb, deg, Nv);
            else
                gemm_all<2, 0, 1><<<gG, 256, 0, stream>>>(a0, a1, 0, 0, 0, 0, 0, 0,
                    WbT, p * 128, KK, out, bias, lnw, lnb, deg, Nv);
        }
    }
    if (full)
        gemm_all<8, 1, 1><<<gG, 256, 0, stream>>>(G[0], G[1], G[2], G[3],
                                                  G[4], G[5], G[6], G[7],
                                                  WbT, 0, KK, out, bias, lnw, lnb,
                                                  deg, Nv);
}